// Round 4
// baseline (241.672 us; speedup 1.0000x reference)
//
#include <hip/hip_runtime.h>

// LIF membrane recurrence:
//   mem[t] = mem[t-1] * 0.25 * (1 - spike[t-1]) + x[t]
//   spike[t] = (mem[t] > 0.5) ? 1 : 0
// x: (T=8, 32,128,32,32) f32; out = spikes, same shape/dtype.
// Spatial slab N = 4194304 elems; each thread owns 4 contiguous elems
// and walks t with stride N.
//
// r2 evidence: VGPR_Count=20 -> compiler sank the 8 upfront loads into the
// dependent chain (serial HBM latencies, 28% HBM, 4% VALU). Fixes:
//  (a) sched_barrier(0) pins all 8 loads before the recurrence chain,
//  (b) nontemporal stores keep the never-re-read output out of L2/L3 so the
//      128 MiB input stays L3-resident (FETCH 65MB -> ~0).
// r3: __builtin_nontemporal_store needs a native clang vector type, not
// HIP_vector_type -> use ext_vector_type(4) float.

#define LIF_T 8
#define LIF_N (32 * 128 * 32 * 32)      // 4194304
#define LIF_N4 (LIF_N / 4)              // 1048576 vec4 columns

typedef float f32x4 __attribute__((ext_vector_type(4)));

__global__ __launch_bounds__(256) void lif_kernel(
    const f32x4* __restrict__ x4, f32x4* __restrict__ o4) {
    const int i = blockIdx.x * 256 + threadIdx.x;   // vec4 column index

    // Phase 1: issue all 8 timestep loads back-to-back (independent addrs).
    f32x4 xs[LIF_T];
#pragma unroll
    for (int t = 0; t < LIF_T; ++t) {
        xs[t] = x4[(size_t)t * LIF_N4 + i];
    }
    // Do not let the scheduler sink these loads into the chain below.
    __builtin_amdgcn_sched_barrier(0);

    float mx = 0.f, my = 0.f, mz = 0.f, mw = 0.f;   // membrane
    float sx = 0.f, sy = 0.f, sz = 0.f, sw = 0.f;   // spike (0/1)

#pragma unroll
    for (int t = 0; t < LIF_T; ++t) {
        // decay factor: 0.25 if no spike last step, else 0.
        // mem*d is EXACT (pow2 or zero); the single add matches numpy's
        // rounding bit-for-bit, so (mem > 0.5) can never flip vs ref.
        const float dx = (sx != 0.f) ? 0.f : 0.25f;
        const float dy = (sy != 0.f) ? 0.f : 0.25f;
        const float dz = (sz != 0.f) ? 0.f : 0.25f;
        const float dw = (sw != 0.f) ? 0.f : 0.25f;
        mx = mx * dx + xs[t].x;
        my = my * dy + xs[t].y;
        mz = mz * dz + xs[t].z;
        mw = mw * dw + xs[t].w;
        sx = (mx > 0.5f) ? 1.f : 0.f;
        sy = (my > 0.5f) ? 1.f : 0.f;
        sz = (mz > 0.5f) ? 1.f : 0.f;
        sw = (mw > 0.5f) ? 1.f : 0.f;
        f32x4 s;
        s.x = sx; s.y = sy; s.z = sz; s.w = sw;
        // Output is write-once, never re-read: nt store bypasses L2/L3 so it
        // doesn't evict the input from Infinity Cache.
        __builtin_nontemporal_store(s, &o4[(size_t)t * LIF_N4 + i]);
    }
}

extern "C" void kernel_launch(void* const* d_in, const int* in_sizes, int n_in,
                              void* d_out, int out_size, void* d_ws, size_t ws_size,
                              hipStream_t stream) {
    const f32x4* x4 = (const f32x4*)d_in[0];
    f32x4* o4 = (f32x4*)d_out;
    const int blocks = LIF_N4 / 256;    // 4096
    lif_kernel<<<blocks, 256, 0, stream>>>(x4, o4);
}

// Round 8
// 240.067 us; speedup vs baseline: 1.0067x; 1.0067x over previous
//
#include <hip/hip_runtime.h>

// LIF membrane recurrence:
//   mem[t] = mem[t-1] * 0.25 * (1 - spike[t-1]) + x[t]
//   spike[t] = (mem[t] > 0.5) ? 1 : 0
// x: (T=8, 32,128,32,32) f32; out = spikes, same shape/dtype.
// Spatial slab N = 4194304 elems; each thread owns one float4 column and
// walks t (stride N). Recurrence is serial in t -> all 8 loads belong to
// one thread; the ONLY way to get memory-level parallelism is to have all
// 8 loads in flight before the dependent chain.
//
// r2/r4 evidence: VGPR_Count=20 both rounds -> sched_barrier(0) failed to
// keep loads live; loads serialized (1 in flight/wave), 28% HBM, 4% VALU.
// nt stores: no FETCH change (Infinity Cache is memory-side), 10% slower.
// Fix: empty asm that CONSUMES all 8 loaded values -> compiler must
// materialize all 8 loads (32 VGPRs) before the chain. Plain stores.

#define LIF_T 8
#define LIF_N (32 * 128 * 32 * 32)      // 4194304
#define LIF_N4 (LIF_N / 4)              // 1048576 vec4 columns

typedef float f32x4 __attribute__((ext_vector_type(4)));

__global__ __launch_bounds__(256) void lif_kernel(
    const f32x4* __restrict__ xin, f32x4* __restrict__ o4) {
    const int i = blockIdx.x * 256 + threadIdx.x;   // vec4 column index
    const f32x4* __restrict__ p = xin + i;

    // Phase 1: 8 independent global_load_dwordx4, all issued before one wait.
    f32x4 v0 = p[0 * LIF_N4];
    f32x4 v1 = p[1 * LIF_N4];
    f32x4 v2 = p[2 * LIF_N4];
    f32x4 v3 = p[3 * LIF_N4];
    f32x4 v4 = p[4 * LIF_N4];
    f32x4 v5 = p[5 * LIF_N4];
    f32x4 v6 = p[6 * LIF_N4];
    f32x4 v7 = p[7 * LIF_N4];
    // Keep-alive: forces all 8 results resident here -> loads cannot be
    // sunk into the chain below (rule #17; sched_barrier alone failed).
    asm volatile("" :: "v"(v0), "v"(v1), "v"(v2), "v"(v3),
                       "v"(v4), "v"(v5), "v"(v6), "v"(v7));

    float mx = 0.f, my = 0.f, mz = 0.f, mw = 0.f;   // membrane
    float sx = 0.f, sy = 0.f, sz = 0.f, sw = 0.f;   // spike (0/1)

    // mem*d is EXACT (d is 0 or 0.25, pow2); the single rounded add matches
    // numpy bit-for-bit, so (mem > 0.5) can never flip vs the reference.
#define LIF_STEP(vt, t)                                                    \
    {                                                                      \
        const float dx = (sx != 0.f) ? 0.f : 0.25f;                        \
        const float dy = (sy != 0.f) ? 0.f : 0.25f;                        \
        const float dz = (sz != 0.f) ? 0.f : 0.25f;                        \
        const float dw = (sw != 0.f) ? 0.f : 0.25f;                        \
        mx = mx * dx + (vt).x;                                             \
        my = my * dy + (vt).y;                                             \
        mz = mz * dz + (vt).z;                                             \
        mw = mw * dw + (vt).w;                                             \
        sx = (mx > 0.5f) ? 1.f : 0.f;                                      \
        sy = (my > 0.5f) ? 1.f : 0.f;                                      \
        sz = (mz > 0.5f) ? 1.f : 0.f;                                      \
        sw = (mw > 0.5f) ? 1.f : 0.f;                                      \
        f32x4 s;                                                           \
        s.x = sx; s.y = sy; s.z = sz; s.w = sw;                            \
        o4[(size_t)(t) * LIF_N4 + i] = s;                                  \
    }

    LIF_STEP(v0, 0)
    LIF_STEP(v1, 1)
    LIF_STEP(v2, 2)
    LIF_STEP(v3, 3)
    LIF_STEP(v4, 4)
    LIF_STEP(v5, 5)
    LIF_STEP(v6, 6)
    LIF_STEP(v7, 7)
#undef LIF_STEP
}

extern "C" void kernel_launch(void* const* d_in, const int* in_sizes, int n_in,
                              void* d_out, int out_size, void* d_ws, size_t ws_size,
                              hipStream_t stream) {
    const f32x4* x4 = (const f32x4*)d_in[0];
    f32x4* o4 = (f32x4*)d_out;
    const int blocks = LIF_N4 / 256;    // 4096
    lif_kernel<<<blocks, 256, 0, stream>>>(x4, o4);
}

// Round 9
// 234.559 us; speedup vs baseline: 1.0303x; 1.0235x over previous
//
#include <hip/hip_runtime.h>

// LIF membrane recurrence:
//   mem[t] = mem[t-1] * 0.25 * (1 - spike[t-1]) + x[t]
//   spike[t] = (mem[t] > 0.5) ? 1 : 0
// x: (T=8, 32,128,32,32) f32; out = spikes. Slab N = 4194304 f32.
//
// r2/r4/r8 evidence: identical ~90us / 2.2 TB/s / VALU 4% across three load
// structures; VGPR 20->28 shows hints didn't restore MLP. Theory: compiler
// wait-epochs drain vmcnt to include the previous store's ack (in-order
// retirement), so waves alternate load-latency / store-ack with nothing in
// flight half the time. Fix: 4 column-streams per thread + 2-deep software
// pipeline (named buffers A/B, static indexing per rule #20), so every data
// wait is a counted vmcnt over loads only and >=4 loads are always in
// flight; stores get 2 epochs of slack and never enter the critical path.

#define LIF_T 8
#define LIF_N (32 * 128 * 32 * 32)      // 4194304 f32
#define LIF_N4 (LIF_N / 4)              // 1048576 vec4 columns
#define NTHREADS (1024 * 256)           // total threads = 262144
#define SSTRIDE NTHREADS                // column stride between a thread's streams

typedef float f32x4 __attribute__((ext_vector_type(4)));

// One LIF step on 4 lanes. mem*d is EXACT (d is 0 or 0.25, pow2); the single
// rounded add matches numpy bit-for-bit, so (mem > 0.5) can never flip.
__device__ __forceinline__ f32x4 lif_step(f32x4& m, f32x4& s, const f32x4 v) {
    m.x = m.x * ((s.x != 0.f) ? 0.f : 0.25f) + v.x;
    m.y = m.y * ((s.y != 0.f) ? 0.f : 0.25f) + v.y;
    m.z = m.z * ((s.z != 0.f) ? 0.f : 0.25f) + v.z;
    m.w = m.w * ((s.w != 0.f) ? 0.f : 0.25f) + v.w;
    s.x = (m.x > 0.5f) ? 1.f : 0.f;
    s.y = (m.y > 0.5f) ? 1.f : 0.f;
    s.z = (m.z > 0.5f) ? 1.f : 0.f;
    s.w = (m.w > 0.5f) ? 1.f : 0.f;
    return s;
}

__global__ __launch_bounds__(256) void lif_kernel(
    const f32x4* __restrict__ x4, f32x4* __restrict__ o4) {
    const int i = blockIdx.x * 256 + threadIdx.x;   // 0..262143
    const f32x4* __restrict__ xp = x4 + i;
    f32x4* __restrict__ op = o4 + i;

    f32x4 a0, a1, a2, a3, b0, b1, b2, b3;           // double-buffered x
    f32x4 m0 = {0,0,0,0}, m1 = {0,0,0,0}, m2 = {0,0,0,0}, m3 = {0,0,0,0};
    f32x4 s0 = {0,0,0,0}, s1 = {0,0,0,0}, s2 = {0,0,0,0}, s3 = {0,0,0,0};

    // Issue 4 independent coalesced dwordx4 loads; fence pins them here.
#define LOAD4(B, t)                                                        \
    B##0 = xp[(size_t)(t) * LIF_N4 + 0 * SSTRIDE];                         \
    B##1 = xp[(size_t)(t) * LIF_N4 + 1 * SSTRIDE];                         \
    B##2 = xp[(size_t)(t) * LIF_N4 + 2 * SSTRIDE];                         \
    B##3 = xp[(size_t)(t) * LIF_N4 + 3 * SSTRIDE];                         \
    asm volatile("" : "+v"(B##0), "+v"(B##1), "+v"(B##2), "+v"(B##3));

#define STEP4(B, t)                                                        \
    op[(size_t)(t) * LIF_N4 + 0 * SSTRIDE] = lif_step(m0, s0, B##0);       \
    op[(size_t)(t) * LIF_N4 + 1 * SSTRIDE] = lif_step(m1, s1, B##1);       \
    op[(size_t)(t) * LIF_N4 + 2 * SSTRIDE] = lif_step(m2, s2, B##2);       \
    op[(size_t)(t) * LIF_N4 + 3 * SSTRIDE] = lif_step(m3, s3, B##3);

    LOAD4(a, 0)
    LOAD4(b, 1)     // 8 loads in flight before any compute
    STEP4(a, 0)
    LOAD4(a, 2)
    STEP4(b, 1)
    LOAD4(b, 3)
    STEP4(a, 2)
    LOAD4(a, 4)
    STEP4(b, 3)
    LOAD4(b, 5)
    STEP4(a, 4)
    LOAD4(a, 6)
    STEP4(b, 5)
    LOAD4(b, 7)
    STEP4(a, 6)
    STEP4(b, 7)
#undef LOAD4
#undef STEP4
}

extern "C" void kernel_launch(void* const* d_in, const int* in_sizes, int n_in,
                              void* d_out, int out_size, void* d_ws, size_t ws_size,
                              hipStream_t stream) {
    const f32x4* x4 = (const f32x4*)d_in[0];
    f32x4* o4 = (f32x4*)d_out;
    lif_kernel<<<1024, 256, 0, stream>>>(x4, o4);   // 1024*256*4 = LIF_N4 cols
}